// Round 2
// baseline (267.160 us; speedup 1.0000x reference)
//
#include <hip/hip_runtime.h>
#include <math.h>

#define B_ 8
#define T_ 4096
#define M_ 1024
#define G_ 16          // output rows per block
#define R_ 31          // input rows touched: G_ + 15 halo
#define EPSF 1e-6f

// out[b,t,m] = gate[m] * (1/S_t) * sum_{d=0}^{15} w[d] * x[b,t-d,m]
// Scatter-accumulate: block owns 16 output rows (16 float4 accumulators per
// thread), streams the 31 contributing input rows in batches of 8 independent
// loads (up to 16 in flight) -> latency-tolerant, no serial load chain.
__global__ __launch_bounds__(256) void bump_conv_kernel(
    const float* __restrict__ x,
    const float* __restrict__ gate_raw,
    float* __restrict__ out) {
  const int groups = T_ / G_;            // 256
  const int grp  = blockIdx.x % groups;
  const int b    = blockIdx.x / groups;
  const int base = grp * G_;
  const int m    = threadIdx.x * 4;      // 256 threads * float4 = M_

  // --- taps ---
  float w[16];
  float S = 0.0f;
#pragma unroll
  for (int d = 0; d < 16; ++d) {
    float u = fminf((float)d * (1.0f / 15.0f), 1.0f - EPSF);
    float den = 1.0f - u * u + EPSF;
    w[d] = expf(1.0f - 1.0f / den);      // d=15 underflows to 0.0f (matches ref)
    S += w[d];
  }
  const float rsS = 1.0f / fmaxf(S, EPSF);

  // --- per-channel gate: softplus(gate_raw) ---
  const float4 graw = *(const float4*)(gate_raw + m);
  float4 g;
  g.x = fmaxf(graw.x, 0.0f) + log1pf(expf(-fabsf(graw.x)));
  g.y = fmaxf(graw.y, 0.0f) + log1pf(expf(-fabsf(graw.y)));
  g.z = fmaxf(graw.z, 0.0f) + log1pf(expf(-fabsf(graw.z)));
  g.w = fmaxf(graw.w, 0.0f) + log1pf(expf(-fabsf(graw.w)));

  const float* xb = x   + (size_t)b * T_ * M_ + m;
  float*       ob = out + (size_t)b * T_ * M_ + m;

  float4 acc[G_];
#pragma unroll
  for (int s = 0; s < G_; ++s) acc[s] = make_float4(0.f, 0.f, 0.f, 0.f);

  // input row j (j=0..30) is t = base - 15 + j; feeds outputs s in
  // [max(0,j-15), min(15,j)] with tap weight w[s + 15 - j].
#define LOADJ(j) \
  ((base - 15 + (j)) >= 0 ? *(const float4*)(xb + (size_t)(base - 15 + (j)) * M_) \
                          : make_float4(0.f, 0.f, 0.f, 0.f))

#define ACCJ(j, v)                                                   \
  do {                                                               \
    _Pragma("unroll")                                                \
    for (int s = 0; s < G_; ++s) {                                   \
      if (s >= (j) - 15 && s <= (j)) {                               \
        const float wd = w[s + 15 - (j)];                            \
        acc[s].x = fmaf(wd, (v).x, acc[s].x);                        \
        acc[s].y = fmaf(wd, (v).y, acc[s].y);                        \
        acc[s].z = fmaf(wd, (v).z, acc[s].z);                        \
        acc[s].w = fmaf(wd, (v).w, acc[s].w);                        \
      }                                                              \
    }                                                                \
  } while (0)

  float4 bufA[8], bufB[8];
  // batch 1+2: j = 0..15 (16 independent loads in flight)
#pragma unroll
  for (int i = 0; i < 8; ++i) bufA[i] = LOADJ(i);
#pragma unroll
  for (int i = 0; i < 8; ++i) bufB[i] = LOADJ(8 + i);

  // consume A (j 0..7), refill A with j 16..23 (t = base+1..base+8, always in range)
#pragma unroll
  for (int i = 0; i < 8; ++i) ACCJ(i, bufA[i]);
#pragma unroll
  for (int i = 0; i < 8; ++i) bufA[i] = *(const float4*)(xb + (size_t)(base + 1 + i) * M_);

  // consume B (j 8..15), refill B with j 24..30 (t = base+9..base+15, in range)
#pragma unroll
  for (int i = 0; i < 8; ++i) ACCJ(8 + i, bufB[i]);
#pragma unroll
  for (int i = 0; i < 7; ++i) bufB[i] = *(const float4*)(xb + (size_t)(base + 9 + i) * M_);

  // consume A (j 16..23), B (j 24..30)
#pragma unroll
  for (int i = 0; i < 8; ++i) ACCJ(16 + i, bufA[i]);
#pragma unroll
  for (int i = 0; i < 7; ++i) ACCJ(24 + i, bufB[i]);

  // --- epilogue: normalize (partial for t<15), gate, store ---
#pragma unroll
  for (int s = 0; s < G_; ++s) {
    float sc = rsS;
    if (s < 15 && base == 0) {           // only group 0; branch folds for s==15
      float p = 0.0f;
#pragma unroll
      for (int d = 0; d < 16; ++d) p += (d <= s) ? w[d] : 0.0f;
      sc = 1.0f / fmaxf(p, EPSF);
    }
    float4 o;
    o.x = acc[s].x * sc * g.x;
    o.y = acc[s].y * sc * g.y;
    o.z = acc[s].z * sc * g.z;
    o.w = acc[s].w * sc * g.w;
    *(float4*)(ob + (size_t)(base + s) * M_) = o;
  }
#undef LOADJ
#undef ACCJ
}

extern "C" void kernel_launch(void* const* d_in, const int* in_sizes, int n_in,
                              void* d_out, int out_size, void* d_ws, size_t ws_size,
                              hipStream_t stream) {
  const float* x        = (const float*)d_in[0];
  // d_in[1] = mask (T,T): redundant (taps already causal) -- intentionally unread.
  const float* gate_raw = (const float*)d_in[2];
  float*       out      = (float*)d_out;

  dim3 grid(B_ * (T_ / G_));   // 2048 blocks
  dim3 block(256);
  bump_conv_kernel<<<grid, block, 0, stream>>>(x, gate_raw, out);
}

// Round 3
// 266.511 us; speedup vs baseline: 1.0024x; 1.0024x over previous
//
#include <hip/hip_runtime.h>
#include <math.h>

#define B_ 8
#define T_ 4096
#define M_ 1024
#define G_ 16          // output rows per block
#define EPSF 1e-6f

// out[b,t,m] = gate[m] * (1/S_t) * sum_{d=0}^{15} w[d] * x[b,t-d,m]
// Block owns 16 output rows. Each thread issues ALL 31 contributing row
// loads up front (31 float4 = 124 VGPRs in flight), then scatter-accumulates
// into 16 float4 accumulators. __launch_bounds__(256,2) caps occupancy at
// 2 waves/EU so the register allocator KEEPS the loads in flight instead of
// serializing them (R2's VGPR=56 < the 64 needed for acc alone proved it
// was spilling/serializing under the default max-occupancy budget).
__global__ __launch_bounds__(256, 2) void bump_conv_kernel(
    const float* __restrict__ x,
    const float* __restrict__ gate_raw,
    float* __restrict__ out) {
  const int groups = T_ / G_;            // 256
  const int grp  = blockIdx.x % groups;
  const int b    = blockIdx.x / groups;
  const int base = grp * G_;
  const int m    = threadIdx.x * 4;      // 256 threads * float4 = M_

  // --- taps (compile-time foldable) ---
  float w[16];
  float S = 0.0f;
#pragma unroll
  for (int d = 0; d < 16; ++d) {
    float u = fminf((float)d * (1.0f / 15.0f), 1.0f - EPSF);
    float den = 1.0f - u * u + EPSF;
    w[d] = expf(1.0f - 1.0f / den);      // d=15 underflows to 0.0f (matches ref)
    S += w[d];
  }
  const float rsS = 1.0f / fmaxf(S, EPSF);

  const float* xb = x   + (size_t)b * T_ * M_ + m;
  float*       ob = out + (size_t)b * T_ * M_ + m;

  // --- issue all 31 independent row loads up front ---
  // row j (0..30) is t = base - 15 + j; t < 0 only possible for grp == 0.
  float4 v[31];
  if (base >= 15) {
#pragma unroll
    for (int j = 0; j < 31; ++j)
      v[j] = *(const float4*)(xb + (size_t)(base - 15 + j) * M_);
  } else {
#pragma unroll
    for (int j = 0; j < 31; ++j)
      v[j] = (base - 15 + j >= 0)
                 ? *(const float4*)(xb + (size_t)(base - 15 + j) * M_)
                 : make_float4(0.f, 0.f, 0.f, 0.f);
  }

  // --- per-channel gate: softplus(gate_raw) (after loads: don't delay issue) ---
  const float4 graw = *(const float4*)(gate_raw + m);
  float4 g;
  g.x = fmaxf(graw.x, 0.0f) + log1pf(expf(-fabsf(graw.x)));
  g.y = fmaxf(graw.y, 0.0f) + log1pf(expf(-fabsf(graw.y)));
  g.z = fmaxf(graw.z, 0.0f) + log1pf(expf(-fabsf(graw.z)));
  g.w = fmaxf(graw.w, 0.0f) + log1pf(expf(-fabsf(graw.w)));

  float4 acc[G_];
#pragma unroll
  for (int s = 0; s < G_; ++s) acc[s] = make_float4(0.f, 0.f, 0.f, 0.f);

  // consume rows in arrival order (progressive vmcnt waits); row j feeds
  // outputs s in [max(0,j-15), min(15,j)] with tap w[s + 15 - j].
#pragma unroll
  for (int j = 0; j < 31; ++j) {
#pragma unroll
    for (int s = 0; s < G_; ++s) {
      if (s >= j - 15 && s <= j) {
        const float wd = w[s + 15 - j];
        acc[s].x = fmaf(wd, v[j].x, acc[s].x);
        acc[s].y = fmaf(wd, v[j].y, acc[s].y);
        acc[s].z = fmaf(wd, v[j].z, acc[s].z);
        acc[s].w = fmaf(wd, v[j].w, acc[s].w);
      }
    }
  }

  // --- epilogue: normalize (partial for t<15), gate, store ---
#pragma unroll
  for (int s = 0; s < G_; ++s) {
    float sc = rsS;
    if (s < 15 && base == 0) {           // wave-uniform; only group 0
      float p = 0.0f;
#pragma unroll
      for (int d = 0; d < 16; ++d) p += (d <= s) ? w[d] : 0.0f;
      sc = 1.0f / fmaxf(p, EPSF);
    }
    float4 o;
    o.x = acc[s].x * sc * g.x;
    o.y = acc[s].y * sc * g.y;
    o.z = acc[s].z * sc * g.z;
    o.w = acc[s].w * sc * g.w;
    *(float4*)(ob + (size_t)(base + s) * M_) = o;
  }
}

extern "C" void kernel_launch(void* const* d_in, const int* in_sizes, int n_in,
                              void* d_out, int out_size, void* d_ws, size_t ws_size,
                              hipStream_t stream) {
  const float* x        = (const float*)d_in[0];
  // d_in[1] = mask (T,T): redundant (taps already causal) -- intentionally unread.
  const float* gate_raw = (const float*)d_in[2];
  float*       out      = (float*)d_out;

  dim3 grid(B_ * (T_ / G_));   // 2048 blocks
  dim3 block(256);
  bump_conv_kernel<<<grid, block, 0, stream>>>(x, gate_raw, out);
}